// Round 6
// baseline (205.396 us; speedup 1.0000x reference)
//
#include <hip/hip_runtime.h>
#include <math.h>

#define LRES 1024
#define TOPK 48
#define NEDGE (LRES*TOPK)

typedef short short8 __attribute__((ext_vector_type(8)));
typedef float f32x4  __attribute__((ext_vector_type(4)));
typedef unsigned int u32;

// ---- output layout (floats). Tuple concat: E, E_idx, E_s, E_idx_sub ----
#define OUT_E     0
#define OUT_EIDX  6291456          // 1024*48*128
#define OUT_ES    6340608          // + 49152
#define OUT_EIDX2 12632064         // + 6291456

// ---- workspace layout (float offsets) ----
#define WS_COORDS 0                // 1024*15 floats
#define WS_DNB    15360            // 49152 floats
#define WS_EIDX   64512            // 49152 ints
#define WS_WPE    113664           // 53248 shorts: W_e packed B-frags
#define WS_WPS    140288           // 163840 shorts: W_s packed B-frags

// RBF recurrence constants.
// edgeE: mu = 2 + r*(4/3), invsig = 0.8  -> u=(d-2)*0.8, Delta = 16/15
#define DE 1.06666667f
#define QE 0.10273976f             // exp(-2*DE^2)
// edgeS: mu = 2 + r*(20/7), invsig = 0.4 -> u=(d-2)*0.4, Delta = 8/7
#define DS 1.14285714f
#define QS 0.07337053f             // exp(-2*DS^2)

// pair -> anchor index maps (N=0, Ca=1, C=2, O=3, Cb=4)
__constant__ int PA[24] = {0,2,3,4,1,1,1,1,0,0,0,4,4,3,0,2,3,4,2,3,4,2,3,2};
__constant__ int PB[24] = {0,2,3,4,0,2,3,4,2,3,4,2,3,2,1,1,1,1,0,0,0,4,4,3};

__device__ inline short f2bf(float f) {           // RNE, off hot path (weights)
    unsigned u = __float_as_uint(f);
    unsigned r = (u + 0x7FFFu + ((u >> 16) & 1u)) >> 16;
    return (short)r;
}

// pack 8 floats -> short8 bf16 by truncation: 1 v_perm per 2 values
__device__ inline short8 pack8(const float* fv) {
    union { short8 s; unsigned u[4]; } r;
    #pragma unroll
    for (int i = 0; i < 4; ++i)
        r.u[i] = __builtin_amdgcn_perm(__float_as_uint(fv[2*i+1]),
                                       __float_as_uint(fv[2*i]), 0x07060302u);
    return r.s;
}

// async global(L2) -> LDS, 16B per lane. LDS dest: wave-uniform base + lane*16.
__device__ __forceinline__ void gload16(const void* g, void* l) {
    __builtin_amdgcn_global_load_lds(
        (const __attribute__((address_space(1))) u32*)g,
        (__attribute__((address_space(3))) u32*)l, 16, 0, 0);
}

// counted-vmcnt barrier: all but the newest N vmem ops drained, then s_barrier.
// sched_barrier fences stop compile-time motion of ds_read/MFMA across it.
#define PIPE_BARRIER(N) do {                                        \
    __builtin_amdgcn_sched_barrier(0);                              \
    asm volatile("s_waitcnt vmcnt(" #N ")" ::: "memory");           \
    __builtin_amdgcn_s_barrier();                                   \
    __builtin_amdgcn_sched_barrier(0);                              \
} while (0)

// In-register LayerNorm + NT store. C layout: row(edge)=quad*4+r, col=nt*16+l16.
// NT: outputs are never re-read on-device; keeps the write stream from
// evicting the L2-resident weights (round-4: FETCH 43MB -> 11MB).
__device__ __forceinline__ void ln_write(const f32x4* acc, float* op,
                                         const float* gv, const float* bv,
                                         int l16, int quad) {
    #pragma unroll
    for (int r = 0; r < 4; ++r) {
        float s = 0.f, s2 = 0.f;
        #pragma unroll
        for (int nt = 0; nt < 8; ++nt) { float x = acc[nt][r]; s += x; s2 = fmaf(x, x, s2); }
        #pragma unroll
        for (int m = 1; m <= 8; m <<= 1) {
            s  += __shfl_xor(s,  m);
            s2 += __shfl_xor(s2, m);
        }
        float mu = s * 0.0078125f;
        float rs = rsqrtf(fmaf(s2, 0.0078125f, -mu*mu) + 1e-5f);
        float* row = op + (quad*4 + r)*128 + l16;
        #pragma unroll
        for (int nt = 0; nt < 8; ++nt)
            __builtin_nontemporal_store(gv[nt]*(acc[nt][r] - mu)*rs + bv[nt],
                                        &row[nt*16]);
    }
}

// ============ K_PRE: topk (blocks 0..255) | pack (256..895) | coords (896..899) =====
__global__ __launch_bounds__(256) void k_pre(const float* __restrict__ X,
                                             const float* __restrict__ mask,
                                             const float* __restrict__ We,
                                             const float* __restrict__ Ws,
                                             float* __restrict__ coords,
                                             short* __restrict__ WpE,
                                             short* __restrict__ WpS,
                                             float* __restrict__ Dnb,
                                             int* __restrict__ Eidx,
                                             float* __restrict__ out) {
    int blk = blockIdx.x, t = threadIdx.x;
    if (blk < 256) {
        // ---------------- top-48 per row, one wave per row ----------------
        __shared__ float sCa[LRES*3];
        __shared__ float sM[LRES];
        for (int j = t; j < LRES; j += 256) {
            sCa[j*3+0] = X[j*111 + 3];
            sCa[j*3+1] = X[j*111 + 4];
            sCa[j*3+2] = X[j*111 + 5];
            sM[j] = mask[j];
        }
        __syncthreads();
        int w = t >> 6, lane = t & 63;
        int i = blk * 4 + w;
        float cx = sCa[i*3], cy = sCa[i*3+1], cz = sCa[i*3+2];
        float mi = sM[i];
        float dv[16], m2v[16];
        float lmax = -1e30f;
        #pragma unroll
        for (int s = 0; s < 16; ++s) {
            int j = s*64 + lane;
            float dx = cx - sCa[j*3], dy = cy - sCa[j*3+1], dz = cz - sCa[j*3+2];
            float d  = __builtin_amdgcn_sqrtf(dx*dx + dy*dy + dz*dz + 1e-6f);
            float m2 = mi * sM[j];
            dv[s] = m2 * d; m2v[s] = m2;
            lmax = fmaxf(lmax, dv[s]);
        }
        #pragma unroll
        for (int off = 32; off; off >>= 1) lmax = fmaxf(lmax, __shfl_xor(lmax, off));
        unsigned long long key[16];
        unsigned long long mkey = ~0ull; int mslot = 0;
        #pragma unroll
        for (int s = 0; s < 16; ++s) {
            float dadj = dv[s] + (1.0f - m2v[s]) * lmax;
            key[s] = (((unsigned long long)__float_as_uint(dadj)) << 10) | (unsigned)(s*64 + lane);
            if (key[s] < mkey) { mkey = key[s]; mslot = s; }
        }
        for (int it = 0; it < TOPK; ++it) {
            unsigned long long wk = mkey;
            #pragma unroll
            for (int off = 32; off; off >>= 1) {
                unsigned long long o = __shfl_xor(wk, off);
                wk = (o < wk) ? o : wk;
            }
            if (lane == 0) {
                int j = (int)(wk & 1023u);
                int id = i*TOPK + it;
                Dnb[id]  = __uint_as_float((unsigned)(wk >> 10));
                Eidx[id] = j;
                __builtin_nontemporal_store((float)j, &out[OUT_EIDX  + id]);
                __builtin_nontemporal_store((float)j, &out[OUT_EIDX2 + id]);
            }
            if (mkey == wk) {
                key[mslot] = ~0ull;
                mkey = ~0ull;
                #pragma unroll
                for (int s = 0; s < 16; ++s)
                    if (key[s] < mkey) { mkey = key[s]; mslot = s; }
            }
        }
    } else if (blk < 896) {
        // -------- pack W_e / W_s into MFMA B-fragment order, (ks*8+nt) major --------
        int g = (blk - 256) * 256 + t;
        if (g < 104*512) {
            int j = g & 7, lane = (g >> 3) & 63, gg = g >> 9;
            int nt = gg & 7, ks = gg >> 3;
            int n = nt*16 + (lane & 15), k = ks*32 + (lane >> 4)*8 + j;
            WpE[g] = f2bf(We[n*416 + k]);
        }
        if (g < 320*512) {
            int j = g & 7, lane = (g >> 3) & 63, gg = g >> 9;
            int nt = gg & 7, ks = gg >> 3;
            // lane's atom group is contiguous: atom = quad*8 + q  (q = ks&7)
            int a = ks >> 3, q = ks & 7, quad = lane >> 4;
            int n = nt*16 + (lane & 15);
            int k = a*256 + quad*64 + q*8 + j;      // = a*256 + atom*8 + rbf
            WpS[g] = f2bf(Ws[n*1280 + k]);
        }
    } else {
        // ---------------- per-residue coords N,Ca,C,O,Cb ----------------
        int r = (blk - 896) * 256 + t;
        if (r >= LRES) return;
        const float* xr = X + r * 111;
        float N[3], Ca[3], C[3], O[3], bv[3], cv[3], av[3];
        #pragma unroll
        for (int d = 0; d < 3; ++d) {
            N[d]  = xr[0*3 + d];  Ca[d] = xr[1*3 + d];
            C[d]  = xr[2*3 + d];  O[d]  = xr[4*3 + d];
            bv[d] = Ca[d] - N[d]; cv[d] = C[d] - Ca[d];
        }
        av[0] = bv[1]*cv[2] - bv[2]*cv[1];
        av[1] = bv[2]*cv[0] - bv[0]*cv[2];
        av[2] = bv[0]*cv[1] - bv[1]*cv[0];
        float* o = coords + r * 15;
        #pragma unroll
        for (int d = 0; d < 3; ++d) {
            float Cb = -0.58273431f*av[d] + 0.56802827f*bv[d] - 0.54067466f*cv[d] + Ca[d];
            o[0*3+d] = N[d]; o[1*3+d] = Ca[d]; o[2*3+d] = C[d];
            o[3*3+d] = O[d]; o[4*3+d] = Cb;
        }
    }
}

// stage one ks-set (8 frags x 1KB) into sBuf[buf]; wave w stages frags w, w+4
#define STAGE3(Wsrc, buf, kss) do {                                             \
    gload16((const short*)(Wsrc) + (((kss)*8 + w)*512)     + lane*8,            \
            &sBuf[buf][w*512]);                                                 \
    gload16((const short*)(Wsrc) + (((kss)*8 + w + 4)*512) + lane*8,            \
            &sBuf[buf][(w+4)*512]);                                             \
} while (0)

// ============ K_EDGE: 1536 blocks; even = edgeS, odd = edgeE ============
// 64 edges/block; each of 4 waves owns 16 edges with FULL K.
// B-fragments staged L2->LDS once per block: triple-buffered 8KB ks-sets,
// depth-2 prefetch, counted-vmcnt raw barriers (loads stay in flight across
// barriers; each load gets ~2 phases to land). Register LN, NT output stores.
__global__ __launch_bounds__(256, 5) void k_edge(const float* __restrict__ coords,
                                                 const float* __restrict__ X,
                                                 const float* __restrict__ amask,
                                                 const short* __restrict__ WpE,
                                                 const short* __restrict__ WpS,
                                                 const float* __restrict__ Dnb,
                                                 const int* __restrict__ Eidx,
                                                 const int* __restrict__ ri,
                                                 const int* __restrict__ ch,
                                                 const float* __restrict__ Wpos,
                                                 const float* __restrict__ bpos,
                                                 const float* __restrict__ ge,
                                                 const float* __restrict__ be,
                                                 const float* __restrict__ gs,
                                                 const float* __restrict__ bs,
                                                 float* __restrict__ out) {
    __shared__ float smemF[992];
    __shared__ __align__(16) short sBuf[3][4096];   // 3 x 8KB B-fragment buffers
    int t = threadIdx.x;
    int w = t >> 6, lane = t & 63, quad = lane >> 4, l16 = lane & 15;
    int idB = (blockIdx.x >> 1) * 64;     // first edge of this block
    int i0  = idB / TOPK;                 // block spans at most 2 residue rows

    if (!(blockIdx.x & 1)) {
        // =============== edgeS: 1280 -> 128 matvec + LN ===============
        float* sA = smemF;                // 30 floats: 2 rows x 15 anchor coords
        if (t < 30) {
            int rr = i0 + t/15; if (rr > LRES-1) rr = LRES-1;
            sA[t] = coords[rr*15 + t%15];
        }
        int id0 = idB + w*16;             // this wave's 16 edges
        int id  = id0 + l16;
        int jn  = Eidx[id];
        int ro  = (id/TOPK - i0)*15;
        // lane's 8 sidechain atoms are contiguous: atoms quad*8 .. quad*8+7
        const float* xp = X + jn*111 + 15 + quad*24;     // 24 floats = 96B
        const float* ap = amask + jn*37 + 5 + quad*8;    // 8 floats
        float Sf[24], am[8];
        #pragma unroll
        for (int c = 0; c < 24; ++c) Sf[c] = xp[c];
        #pragma unroll
        for (int c = 0; c < 8; ++c)  am[c] = ap[c];

        STAGE3(WpS, 0, 0);
        STAGE3(WpS, 1, 1);
        __syncthreads();                  // sA visible; buf0,buf1 staged (full drain, once)

        f32x4 acc[8] = {};
        int cur = 0;
        #pragma unroll 1
        for (int ks = 0; ks < 40; ++ks) {
            if (ks + 2 < 40) {
                int st = cur + 2; if (st >= 3) st -= 3;
                STAGE3(WpS, st, ks + 2);
            }
            int a = ks >> 3, q = ks & 7;
            float dx = sA[ro + a*3 + 0] - Sf[q*3 + 0];
            float dy = sA[ro + a*3 + 1] - Sf[q*3 + 1];
            float dz = sA[ro + a*3 + 2] - Sf[q*3 + 2];
            float d  = __builtin_amdgcn_sqrtf(fmaf(dz,dz,fmaf(dy,dy,fmaf(dx,dx,1e-6f))));
            float u  = fmaf(d, 0.4f, -0.8f);
            float e0 = __expf(-u*u) * am[q];
            float g  = __expf(fmaf(2.0f*DS, u, -DS*DS));
            float fv[8];
            fv[0] = e0;
            #pragma unroll
            for (int r = 1; r < 8; ++r) { e0 *= g; g *= QS; fv[r] = e0; }
            short8 af = pack8(fv);
            const short8* bb = (const short8*)sBuf[cur];
            #pragma unroll
            for (int nt = 0; nt < 8; ++nt) {
                short8 b = bb[nt*64 + lane];
                acc[nt] = __builtin_amdgcn_mfma_f32_16x16x32_bf16(af, b, acc[nt], 0,0,0);
            }
            if (ks < 39) {
                if (ks + 2 < 40) PIPE_BARRIER(2);
                else             PIPE_BARRIER(0);
                if (++cur == 3) cur = 0;
            }
        }
        float gv[8], bv[8];
        #pragma unroll
        for (int nt = 0; nt < 8; ++nt) { gv[nt] = gs[nt*16+l16]; bv[nt] = bs[nt*16+l16]; }
        ln_write(acc, out + OUT_ES + (size_t)id0*128, gv, bv, l16, quad);
    } else {
        // =============== edgeE: 416 -> 128 matvec + LN ===============
        float* sA = smemF;                // 32  (2 rows x 15)
        float* sB = smemF + 32;           // 960 (64 x 15 neighbor coords)

        if (t < 30) {
            int rr = i0 + t/15; if (rr > LRES-1) rr = LRES-1;
            sA[t] = coords[rr*15 + t%15];
        }
        for (int it = t; it < 64*15; it += 256) {
            int e2 = it/15, q2 = it%15;
            int j2 = Eidx[idB + e2];
            sB[e2*15+q2] = coords[j2*15+q2];
        }
        int id0 = idB + w*16;
        int e   = w*16 + l16;             // this lane's edge within block
        int id  = id0 + l16;
        int jn  = Eidx[id];
        int ii  = id / TOPK;
        float dnb = Dnb[id];
        int offr = ri[ii] - ri[jn];
        int dpos = (ch[ii] == ch[jn]) ? min(max(offr + 32, 0), 64) : 65;
        float pf[8];
        #pragma unroll
        for (int c = 0; c < 8; ++c) {
            int cc = (quad & 1)*8 + c;
            pf[c] = Wpos[cc*66 + dpos] + bpos[cc];
        }
        int roe = (ii - i0)*15;
        float rb = (quad & 1) ? 8.0f*DE : 0.0f;

        STAGE3(WpE, 0, 0);
        STAGE3(WpE, 1, 1);
        __syncthreads();

        f32x4 acc[8] = {};
        int cur = 0;
        #pragma unroll 1
        for (int ks = 0; ks < 13; ++ks) {
            if (ks + 2 < 13) {
                int st = cur + 2; if (st >= 3) st -= 3;
                STAGE3(WpE, st, ks + 2);
            }
            float fv[8];
            if (ks == 0 && quad < 2) {
                #pragma unroll
                for (int c = 0; c < 8; ++c) fv[c] = pf[c];
            } else {
                float d;
                if (ks == 0) {
                    d = dnb;
                } else {
                    int p  = 2*ks - 2 + (quad >> 1);   // pair index
                    int pa = PA[p], pb = PB[p];
                    float dx = sA[roe+pa*3+0] - sB[e*15+pb*3+0];
                    float dy = sA[roe+pa*3+1] - sB[e*15+pb*3+1];
                    float dz = sA[roe+pa*3+2] - sB[e*15+pb*3+2];
                    d = __builtin_amdgcn_sqrtf(dx*dx + dy*dy + dz*dz + 1e-6f);
                }
                float u  = fmaf(d, 0.8f, -1.6f) - rb;
                float e0 = __expf(-u*u);
                float g  = __expf(fmaf(2.0f*DE, u, -DE*DE));
                fv[0] = e0;
                #pragma unroll
                for (int r = 1; r < 8; ++r) { e0 *= g; g *= QE; fv[r] = e0; }
            }
            short8 af = pack8(fv);
            const short8* bb = (const short8*)sBuf[cur];
            #pragma unroll
            for (int nt = 0; nt < 8; ++nt) {
                short8 b = bb[nt*64 + lane];
                acc[nt] = __builtin_amdgcn_mfma_f32_16x16x32_bf16(af, b, acc[nt], 0,0,0);
            }
            if (ks < 12) {
                if (ks + 2 < 13) PIPE_BARRIER(2);
                else             PIPE_BARRIER(0);
                if (++cur == 3) cur = 0;
            }
        }
        float gv[8], bv[8];
        #pragma unroll
        for (int nt = 0; nt < 8; ++nt) { gv[nt] = ge[nt*16+l16]; bv[nt] = be[nt*16+l16]; }
        ln_write(acc, out + OUT_E + (size_t)id0*128, gv, bv, l16, quad);
    }
}

extern "C" void kernel_launch(void* const* d_in, const int* in_sizes, int n_in,
                              void* d_out, int out_size, void* d_ws, size_t ws_size,
                              hipStream_t stream) {
    (void)in_sizes; (void)n_in; (void)out_size; (void)ws_size;
    const float* X     = (const float*)d_in[0];
    const float* mask  = (const float*)d_in[2];
    const float* amask = (const float*)d_in[3];
    const int*   ri    = (const int*)d_in[4];
    const int*   ch    = (const int*)d_in[6];
    const float* Wpos  = (const float*)d_in[7];
    const float* bpos  = (const float*)d_in[8];
    const float* We    = (const float*)d_in[9];
    const float* ge    = (const float*)d_in[10];
    const float* be    = (const float*)d_in[11];
    const float* Ws    = (const float*)d_in[12];
    const float* gs    = (const float*)d_in[13];
    const float* bs    = (const float*)d_in[14];

    float* out    = (float*)d_out;
    float* ws     = (float*)d_ws;
    float* coords = ws + WS_COORDS;
    float* Dnb    = ws + WS_DNB;
    int*   Eidx   = (int*)(ws + WS_EIDX);
    short* WpE    = (short*)(ws + WS_WPE);
    short* WpS    = (short*)(ws + WS_WPS);

    k_pre <<<dim3(900),  dim3(256), 0, stream>>>(X, mask, We, Ws, coords,
                                                 WpE, WpS, Dnb, Eidx, out);
    k_edge<<<dim3(1536), dim3(256), 0, stream>>>(coords, X, amask, WpE, WpS,
                                                 Dnb, Eidx, ri, ch, Wpos, bpos,
                                                 ge, be, gs, bs, out);
}

// Round 7
// 182.921 us; speedup vs baseline: 1.1229x; 1.1229x over previous
//
#include <hip/hip_runtime.h>
#include <math.h>

#define LRES 1024
#define TOPK 48
#define NEDGE (LRES*TOPK)

typedef short short8 __attribute__((ext_vector_type(8)));
typedef float f32x4  __attribute__((ext_vector_type(4)));

// ---- output layout (floats). Tuple concat: E, E_idx, E_s, E_idx_sub ----
#define OUT_E     0
#define OUT_EIDX  6291456          // 1024*48*128
#define OUT_ES    6340608          // + 49152
#define OUT_EIDX2 12632064         // + 6291456

// ---- workspace layout (float offsets) ----
#define WS_COORDS 0                // 1024*15 floats
#define WS_DNB    15360            // 49152 floats
#define WS_EIDX   64512            // 49152 ints
#define WS_WPE    113664           // 53248 shorts: W_e packed B-frags
#define WS_WPS    140288           // 163840 shorts: W_s packed B-frags

// RBF recurrence constants.
// edgeE: mu = 2 + r*(4/3), invsig = 0.8  -> u=(d-2)*0.8, Delta = 16/15
#define DE 1.06666667f
#define QE 0.10273976f             // exp(-2*DE^2)
// edgeS: mu = 2 + r*(20/7), invsig = 0.4 -> u=(d-2)*0.4, Delta = 8/7
#define DS 1.14285714f
#define QS 0.07337053f             // exp(-2*DS^2)

// pair -> anchor index maps (N=0, Ca=1, C=2, O=3, Cb=4)
__constant__ int PA[24] = {0,2,3,4,1,1,1,1,0,0,0,4,4,3,0,2,3,4,2,3,4,2,3,2};
__constant__ int PB[24] = {0,2,3,4,0,2,3,4,2,3,4,2,3,2,1,1,1,1,0,0,0,4,4,3};

__device__ inline short f2bf(float f) {           // RNE, off hot path (weights)
    unsigned u = __float_as_uint(f);
    unsigned r = (u + 0x7FFFu + ((u >> 16) & 1u)) >> 16;
    return (short)r;
}

// pack 8 floats -> short8 bf16 by truncation: 1 v_perm per 2 values
__device__ inline short8 pack8(const float* fv) {
    union { short8 s; unsigned u[4]; } r;
    #pragma unroll
    for (int i = 0; i < 4; ++i)
        r.u[i] = __builtin_amdgcn_perm(__float_as_uint(fv[2*i+1]),
                                       __float_as_uint(fv[2*i]), 0x07060302u);
    return r.s;
}

// K-split reduction + LayerNorm + NT store, constant-time epilogue.
// Each wave writes its partial acc to a DISJOINT hb region (no serialized
// accumulate rounds, no RMW). Then thread (e,c) sums 4 partials for its 8
// columns, LN-stats via 4-step shfl butterfly (16-thread groups are
// wave-contiguous), and stores straight from registers. hb = 4*16*134 floats.
__device__ __forceinline__ void kred_ln(const f32x4 (*acc)[8], float* hb,
                                        float* outp, const float* g,
                                        const float* b, int t, int w,
                                        int quad, int l16) {
    int e = t >> 4, c = t & 15;
    float gv[8], bv[8];
    #pragma unroll
    for (int k = 0; k < 8; ++k) { gv[k] = g[c + 16*k]; bv[k] = b[c + 16*k]; }
    float* hw = hb + w*2144;
    #pragma unroll
    for (int mt = 0; mt < 2; ++mt) {
        __syncthreads();                       // hb free (K-loop / prev pass done)
        #pragma unroll
        for (int nt = 0; nt < 8; ++nt)
        #pragma unroll
        for (int r = 0; r < 4; ++r)
            hw[(quad*4 + r)*134 + nt*16 + l16] = acc[mt][nt][r];
        __syncthreads();
        float s = 0.f, s2 = 0.f, vals[8];
        #pragma unroll
        for (int k = 0; k < 8; ++k) {
            int col = e*134 + c + 16*k;
            float v = hb[col] + hb[2144 + col] + hb[4288 + col] + hb[6432 + col];
            vals[k] = v; s += v; s2 = fmaf(v, v, s2);
        }
        #pragma unroll
        for (int m = 1; m <= 8; m <<= 1) {
            s  += __shfl_xor(s,  m);
            s2 += __shfl_xor(s2, m);
        }
        float mu = s * 0.0078125f;
        float rs = rsqrtf(fmaf(s2, 0.0078125f, -mu*mu) + 1e-5f);
        float* row = outp + (size_t)(mt*16 + e)*128 + c;
        #pragma unroll
        for (int k = 0; k < 8; ++k)
            __builtin_nontemporal_store(gv[k]*(vals[k] - mu)*rs + bv[k],
                                        &row[16*k]);
    }
}

// ============ K_PRE: topk (blocks 0..255) | pack (256..895) | coords (896..899) =====
__global__ __launch_bounds__(256) void k_pre(const float* __restrict__ X,
                                             const float* __restrict__ mask,
                                             const float* __restrict__ We,
                                             const float* __restrict__ Ws,
                                             float* __restrict__ coords,
                                             short* __restrict__ WpE,
                                             short* __restrict__ WpS,
                                             float* __restrict__ Dnb,
                                             int* __restrict__ Eidx,
                                             float* __restrict__ out) {
    int blk = blockIdx.x, t = threadIdx.x;
    if (blk < 256) {
        // ---------------- top-48 per row, one wave per row ----------------
        __shared__ float sCa[LRES*3];
        __shared__ float sM[LRES];
        for (int j = t; j < LRES; j += 256) {
            sCa[j*3+0] = X[j*111 + 3];
            sCa[j*3+1] = X[j*111 + 4];
            sCa[j*3+2] = X[j*111 + 5];
            sM[j] = mask[j];
        }
        __syncthreads();
        int w = t >> 6, lane = t & 63;
        int i = blk * 4 + w;
        float cx = sCa[i*3], cy = sCa[i*3+1], cz = sCa[i*3+2];
        float mi = sM[i];
        float dv[16], m2v[16];
        float lmax = -1e30f;
        #pragma unroll
        for (int s = 0; s < 16; ++s) {
            int j = s*64 + lane;
            float dx = cx - sCa[j*3], dy = cy - sCa[j*3+1], dz = cz - sCa[j*3+2];
            float d  = __builtin_amdgcn_sqrtf(dx*dx + dy*dy + dz*dz + 1e-6f);
            float m2 = mi * sM[j];
            dv[s] = m2 * d; m2v[s] = m2;
            lmax = fmaxf(lmax, dv[s]);
        }
        #pragma unroll
        for (int off = 32; off; off >>= 1) lmax = fmaxf(lmax, __shfl_xor(lmax, off));
        unsigned long long key[16];
        unsigned long long mkey = ~0ull; int mslot = 0;
        #pragma unroll
        for (int s = 0; s < 16; ++s) {
            float dadj = dv[s] + (1.0f - m2v[s]) * lmax;
            key[s] = (((unsigned long long)__float_as_uint(dadj)) << 10) | (unsigned)(s*64 + lane);
            if (key[s] < mkey) { mkey = key[s]; mslot = s; }
        }
        for (int it = 0; it < TOPK; ++it) {
            unsigned long long wk = mkey;
            #pragma unroll
            for (int off = 32; off; off >>= 1) {
                unsigned long long o = __shfl_xor(wk, off);
                wk = (o < wk) ? o : wk;
            }
            if (lane == 0) {
                int j = (int)(wk & 1023u);
                int id = i*TOPK + it;
                Dnb[id]  = __uint_as_float((unsigned)(wk >> 10));
                Eidx[id] = j;
                out[OUT_EIDX  + id] = (float)j;
                out[OUT_EIDX2 + id] = (float)j;
            }
            if (mkey == wk) {
                key[mslot] = ~0ull;
                mkey = ~0ull;
                #pragma unroll
                for (int s = 0; s < 16; ++s)
                    if (key[s] < mkey) { mkey = key[s]; mslot = s; }
            }
        }
    } else if (blk < 896) {
        // ---------------- pack W_e / W_s into MFMA B-fragment order ----------------
        int g = (blk - 256) * 256 + t;
        if (g < 8*13*64*8) {
            int j = g & 7, lane = (g >> 3) & 63, gg = g >> 9;
            int ks = gg % 13, nt = gg / 13;
            int n = nt*16 + (lane & 15), k = ks*32 + (lane >> 4)*8 + j;
            WpE[g] = f2bf(We[n*416 + k]);
        }
        if (g < 8*40*64*8) {
            int j = g & 7, lane = (g >> 3) & 63, gg = g >> 9;
            int ks = gg % 40, nt = gg / 40;
            int n = nt*16 + (lane & 15), k = ks*32 + (lane >> 4)*8 + j;
            WpS[g] = f2bf(Ws[n*1280 + k]);
        }
    } else {
        // ---------------- per-residue coords N,Ca,C,O,Cb ----------------
        int r = (blk - 896) * 256 + t;
        if (r >= LRES) return;
        const float* xr = X + r * 111;
        float N[3], Ca[3], C[3], O[3], bv[3], cv[3], av[3];
        #pragma unroll
        for (int d = 0; d < 3; ++d) {
            N[d]  = xr[0*3 + d];  Ca[d] = xr[1*3 + d];
            C[d]  = xr[2*3 + d];  O[d]  = xr[4*3 + d];
            bv[d] = Ca[d] - N[d]; cv[d] = C[d] - Ca[d];
        }
        av[0] = bv[1]*cv[2] - bv[2]*cv[1];
        av[1] = bv[2]*cv[0] - bv[0]*cv[2];
        av[2] = bv[0]*cv[1] - bv[1]*cv[0];
        float* o = coords + r * 15;
        #pragma unroll
        for (int d = 0; d < 3; ++d) {
            float Cb = -0.58273431f*av[d] + 0.56802827f*bv[d] - 0.54067466f*cv[d] + Ca[d];
            o[0*3+d] = N[d]; o[1*3+d] = Ca[d]; o[2*3+d] = C[d];
            o[3*3+d] = O[d]; o[4*3+d] = Cb;
        }
    }
}

// ============ K_EDGE: edgeS (blocks 0..1535) | edgeE (1536..3071) ============
// Baseline structure (round-0, measured-best): 32 edges/block, 4 waves,
// K-split across waves, per-wave B-reads from L2 (weights stay L2-resident).
// New: constant-time epilogue (disjoint partials + register LN), NT stores.
__global__ __launch_bounds__(256, 2) void k_edge(const float* __restrict__ coords,
                                                 const float* __restrict__ X,
                                                 const float* __restrict__ amask,
                                                 const short* __restrict__ WpE,
                                                 const short* __restrict__ WpS,
                                                 const float* __restrict__ Dnb,
                                                 const int* __restrict__ Eidx,
                                                 const int* __restrict__ ri,
                                                 const int* __restrict__ ch,
                                                 const float* __restrict__ Wpos,
                                                 const float* __restrict__ bpos,
                                                 const float* __restrict__ ge,
                                                 const float* __restrict__ be,
                                                 const float* __restrict__ gs,
                                                 const float* __restrict__ bs,
                                                 float* __restrict__ out) {
    __shared__ float smem[9536];
    int t = threadIdx.x;
    int w = t >> 6, lane = t & 63, quad = lane >> 4, l16 = lane & 15;
    float* hb = smem;                          // 4*2144 = 8576: partials buffer

    if (blockIdx.x < 1536) {
        // =============== edgeS: 1280 -> 128 matvec + LN ===============
        float* sA3 = smem + 8576;              // 45
        int id0 = blockIdx.x * 32;
        int i0 = id0 / TOPK;

        if (t < 45) {
            int rr = i0 + t / 15;
            if (rr > LRES-1) rr = LRES-1;
            sA3[t] = coords[rr*15 + t%15];
        }
        // per-lane register operands
        int s1 = 4*w + quad;                   // sidechain atom for half 0
        float S[2][2][3], am[2][2];
        int im[2];
        #pragma unroll
        for (int mt = 0; mt < 2; ++mt) {
            int id = id0 + mt*16 + l16;
            int j  = Eidx[id];
            im[mt] = id / TOPK;
            const float* xp = X + (j*37 + 5)*3;
            const float* ap = amask + j*37 + 5;
            #pragma unroll
            for (int h = 0; h < 2; ++h) {
                int s = s1 + h*16;
                S[mt][h][0] = xp[s*3+0];
                S[mt][h][1] = xp[s*3+1];
                S[mt][h][2] = xp[s*3+2];
                am[mt][h]   = ap[s];
            }
        }
        __syncthreads();

        f32x4 acc[2][8] = {};
        const short8* bp = (const short8*)WpS;

        for (int a = 0; a < 5; ++a) {
            float A[2][3];
            #pragma unroll
            for (int mt = 0; mt < 2; ++mt) {
                int base = (im[mt] - i0)*15 + a*3;
                A[mt][0] = sA3[base+0];
                A[mt][1] = sA3[base+1];
                A[mt][2] = sA3[base+2];
            }
            #pragma unroll
            for (int h = 0; h < 2; ++h) {
                int ks = a*8 + w + h*4;
                short8 afrag[2];
                #pragma unroll
                for (int mt = 0; mt < 2; ++mt) {
                    float dx = A[mt][0] - S[mt][h][0];
                    float dy = A[mt][1] - S[mt][h][1];
                    float dz = A[mt][2] - S[mt][h][2];
                    float d  = __builtin_amdgcn_sqrtf(fmaf(dz,dz,fmaf(dy,dy,fmaf(dx,dx,1e-6f))));
                    float u  = fmaf(d, 0.4f, -0.8f);
                    float e0 = __expf(-u*u) * am[mt][h];
                    float g  = __expf(fmaf(2.0f*DS, u, -DS*DS));
                    float fv[8];
                    fv[0] = e0;
                    #pragma unroll
                    for (int r = 1; r < 8; ++r) { e0 *= g; g *= QS; fv[r] = e0; }
                    afrag[mt] = pack8(fv);
                }
                #pragma unroll
                for (int nt = 0; nt < 8; ++nt) {
                    short8 b = bp[(nt*40 + ks)*64 + lane];
                    acc[0][nt] = __builtin_amdgcn_mfma_f32_16x16x32_bf16(afrag[0], b, acc[0][nt], 0,0,0);
                    acc[1][nt] = __builtin_amdgcn_mfma_f32_16x16x32_bf16(afrag[1], b, acc[1][nt], 0,0,0);
                }
            }
        }
        kred_ln(acc, hb, out + OUT_ES + (size_t)id0*128, gs, bs, t, w, quad, l16);
    } else {
        // =============== edgeE: 416 -> 128 matvec + LN ===============
        float* sA    = smem + 8576;            // 480 (32 x 15)
        float* sB    = smem + 9056;            // 480 (32 x 15)
        float* sdist = hb;                     // 864 (32 x 27), dead before epilogue
        float* sposf = hb + 864;               // 544 (32 x 17)
        int*   sdpos = (int*)(hb + 1408);      // 32
        int id0 = (blockIdx.x - 1536) * 32;

        if (t < 32) {
            int id = id0 + t, i = id / TOPK, j = Eidx[id];
            int off = ri[i] - ri[j];
            sdpos[t] = (ch[i] == ch[j]) ? min(max(off + 32, 0), 64) : 65;
            sdist[t*27] = Dnb[id];
        }
        for (int it = t; it < 32*15; it += 256) {
            int e = it / 15, q = it % 15;
            int id = id0 + e, i = id / TOPK, j = Eidx[id];
            sA[e*15+q] = coords[i*15+q];
            sB[e*15+q] = coords[j*15+q];
        }
        __syncthreads();
        for (int it = t; it < 32*24; it += 256) {
            int e = it / 24, p = it % 24, a = PA[p], b = PB[p];
            float dx = sA[e*15+a*3+0] - sB[e*15+b*3+0];
            float dy = sA[e*15+a*3+1] - sB[e*15+b*3+1];
            float dz = sA[e*15+a*3+2] - sB[e*15+b*3+2];
            sdist[e*27 + 1 + p] = __builtin_amdgcn_sqrtf(dx*dx + dy*dy + dz*dz + 1e-6f);
        }
        for (int it = t; it < 32*16; it += 256) {
            int e = it >> 4, c = it & 15;
            sposf[e*17 + c] = Wpos[c*66 + sdpos[e]] + bpos[c];
        }
        __syncthreads();

        f32x4 acc[2][8] = {};
        const short8* bp = (const short8*)WpE;
        float rb = (quad & 1) ? 8.0f*DE : 0.0f;

        for (int ks = w; ks < 13; ks += 4) {
            short8 afrag[2];
            #pragma unroll
            for (int mt = 0; mt < 2; ++mt) {
                int e = mt*16 + l16;
                float fv[8];
                if (ks == 0 && quad < 2) {
                    #pragma unroll
                    for (int j = 0; j < 8; ++j) fv[j] = sposf[e*17 + quad*8 + j];
                } else {
                    int p = (ks == 0) ? 0 : (2*ks - 1 + (quad >> 1));
                    float d = sdist[e*27 + p];
                    float u = fmaf(d, 0.8f, -1.6f) - rb;
                    float e0 = __expf(-u*u);
                    float g  = __expf(fmaf(2.0f*DE, u, -DE*DE));
                    fv[0] = e0;
                    #pragma unroll
                    for (int r = 1; r < 8; ++r) { e0 *= g; g *= QE; fv[r] = e0; }
                }
                afrag[mt] = pack8(fv);
            }
            #pragma unroll
            for (int nt = 0; nt < 8; ++nt) {
                short8 b = bp[(nt*13 + ks)*64 + lane];
                acc[0][nt] = __builtin_amdgcn_mfma_f32_16x16x32_bf16(afrag[0], b, acc[0][nt], 0,0,0);
                acc[1][nt] = __builtin_amdgcn_mfma_f32_16x16x32_bf16(afrag[1], b, acc[1][nt], 0,0,0);
            }
        }
        kred_ln(acc, hb, out + OUT_E + (size_t)id0*128, ge, be, t, w, quad, l16);
    }
}

extern "C" void kernel_launch(void* const* d_in, const int* in_sizes, int n_in,
                              void* d_out, int out_size, void* d_ws, size_t ws_size,
                              hipStream_t stream) {
    (void)in_sizes; (void)n_in; (void)out_size; (void)ws_size;
    const float* X     = (const float*)d_in[0];
    const float* mask  = (const float*)d_in[2];
    const float* amask = (const float*)d_in[3];
    const int*   ri    = (const int*)d_in[4];
    const int*   ch    = (const int*)d_in[6];
    const float* Wpos  = (const float*)d_in[7];
    const float* bpos  = (const float*)d_in[8];
    const float* We    = (const float*)d_in[9];
    const float* ge    = (const float*)d_in[10];
    const float* be    = (const float*)d_in[11];
    const float* Ws    = (const float*)d_in[12];
    const float* gs    = (const float*)d_in[13];
    const float* bs    = (const float*)d_in[14];

    float* out    = (float*)d_out;
    float* ws     = (float*)d_ws;
    float* coords = ws + WS_COORDS;
    float* Dnb    = ws + WS_DNB;
    int*   Eidx   = (int*)(ws + WS_EIDX);
    short* WpE    = (short*)(ws + WS_WPE);
    short* WpS    = (short*)(ws + WS_WPS);

    k_pre <<<dim3(900),  dim3(256), 0, stream>>>(X, mask, We, Ws, coords,
                                                 WpE, WpS, Dnb, Eidx, out);
    k_edge<<<dim3(3072), dim3(256), 0, stream>>>(coords, X, amask, WpE, WpS,
                                                 Dnb, Eidx, ri, ch, Wpos, bpos,
                                                 ge, be, gs, bs, out);
}